// Round 8
// baseline (272.350 us; speedup 1.0000x reference)
//
#include <hip/hip_runtime.h>
#include <hip/hip_bf16.h>
#include <stdint.h>

// WanSelfAttention on gfx950, round 14: counted-vmcnt pipelines (T4) in the
// two hot loops -- never drain vmcnt(0) per tile.
// attn8: 3 LDS buffers (48K, 3 blocks/CU unchanged), prefetch depth 2;
//   per tile: s_waitcnt vmcnt(4)+s_barrier (tile t's loads issued 2 iters
//   ago -> ~0 wait; t+1's 4 loads stay in flight across the barrier).
// gemm_bt: 2 buffers, barrier -> STAGE(t+1) -> vmcnt(8)+barrier (waits only
//   tile t's 8 loads, issued a full iteration ago).
// Waits are single asm blocks with "memory" clobber to pin ordering.

#define DIM  1536
#define NH   12
#define HD   128
#define LSEQ 2400
#define LPAD 2432
#define KT2  32
#define NT2  (LPAD / KT2)    // 76 global 32-key tiles
#define NTQ  19              // tiles per quarter

typedef __attribute__((ext_vector_type(8))) short short8;
typedef __attribute__((ext_vector_type(8))) _Float16 half8;
typedef __attribute__((ext_vector_type(4))) float f32x4;
typedef unsigned short ushort_t;
typedef unsigned int   uint32;

__device__ __forceinline__ ushort_t f2bf(float f) {
  union { float f; unsigned u; } v; v.f = f;
  unsigned r = (v.u + 0x7fffu + ((v.u >> 16) & 1u)) >> 16;   // RNE
  return (ushort_t)r;
}
__device__ __forceinline__ float bf2f(ushort_t h) {
  union { unsigned u; float f; } v; v.u = ((unsigned)h) << 16;
  return v.f;
}
__device__ __forceinline__ uint32 cvtpk(float lo, float hi) {
  uint32 r;
  asm("v_cvt_pk_bf16_f32 %0, %1, %2" : "=v"(r) : "v"(lo), "v"(hi));
  return r;
}
__device__ __forceinline__ void async16(void* lds, const void* g) {
  __builtin_amdgcn_global_load_lds(
      (const __attribute__((address_space(1))) uint32*)g,
      (__attribute__((address_space(3))) uint32*)lds, 16, 0, 0);
}
__device__ __forceinline__ uint4 pack8(const float* f) {
  uint4 u;
  u.x = (uint32)f2bf(f[0]) | ((uint32)f2bf(f[1]) << 16);
  u.y = (uint32)f2bf(f[2]) | ((uint32)f2bf(f[3]) << 16);
  u.z = (uint32)f2bf(f[4]) | ((uint32)f2bf(f[5]) << 16);
  u.w = (uint32)f2bf(f[6]) | ((uint32)f2bf(f[7]) << 16);
  return u;
}

// ---------------------------------------------------------------------------
// All f32->bf16 conversions in one launch. y=0: x (pad to LPAD, zeros);
// y=1..4: Wq/Wk/Wv/Wo.
// ---------------------------------------------------------------------------
__global__ void cvt_all(const float* __restrict__ x,
                        const float* __restrict__ W0, const float* __restrict__ W1,
                        const float* __restrict__ W2, const float* __restrict__ W3,
                        ushort_t* __restrict__ xd,
                        ushort_t* __restrict__ d0, ushort_t* __restrict__ d1,
                        ushort_t* __restrict__ d2, ushort_t* __restrict__ d3)
{
  const int z = blockIdx.y;
  const int i = blockIdx.x * 256 + threadIdx.x;
  if (z == 0) {
    uint4 u = {0, 0, 0, 0};
    if (i * 8 < LSEQ * DIM) {
      float f[8];
      *(float4*)f = *(const float4*)(x + i * 8);
      *(float4*)(f + 4) = *(const float4*)(x + i * 8 + 4);
      u = pack8(f);
    }
    *(uint4*)(xd + i * 8) = u;
    return;
  }
  if (blockIdx.x >= DIM * DIM / 2048) return;
  const float* s = (z == 1) ? W0 : ((z == 2) ? W1 : ((z == 3) ? W2 : W3));
  ushort_t* d    = (z == 1) ? d0 : ((z == 2) ? d1 : ((z == 3) ? d2 : d3));
  float f[8];
  *(float4*)f = *(const float4*)(s + i * 8);
  *(float4*)(f + 4) = *(const float4*)(s + i * 8 + 4);
  *(uint4*)(d + i * 8) = pack8(f);
}

// ---------------------------------------------------------------------------
// GEMM: C[m,n] = sum_k A[m,k]*B[n,k] + bias[n]. Double-buffered async LDS
// staging with counted vmcnt: barrier (buf overwrite-safe) -> STAGE(t+1) ->
// vmcnt(8)+barrier (tile t data landed; t+1's 8 loads stay in flight).
// XCD-swizzled blockIdx.
// ---------------------------------------------------------------------------
template<int OUT_F32>
__global__ __launch_bounds__(256) void gemm_bt(
    const ushort_t* __restrict__ Ap,
    const ushort_t* __restrict__ B0, const ushort_t* __restrict__ B1, const ushort_t* __restrict__ B2,
    const float* __restrict__ b0, const float* __restrict__ b1, const float* __restrict__ b2,
    void* __restrict__ D0, void* __restrict__ D1, void* __restrict__ D2,
    int Mout)
{
  const int z = blockIdx.y;
  const ushort_t* Bw  = (z == 0) ? B0 : ((z == 1) ? B1 : B2);
  const float* bias   = (z == 0) ? b0 : ((z == 1) ? b1 : b2);
  void* D             = (z == 0) ? D0 : ((z == 1) ? D1 : D2);

  // bijective XCD swizzle for nwg=228: q=28, r=4
  const int bid = blockIdx.x;
  const int x_ = bid & 7, k_ = bid >> 3;
  const int swz = (x_ < 4 ? x_ * 29 : 116 + (x_ - 4) * 28) + k_;
  const int bm = swz / 12, bn = swz % 12;
  const int tid = threadIdx.x;
  const int w = tid >> 6, lam = tid & 63;
  const int wr = w >> 1, wc = w & 1;
  const int lane15 = lam & 15, quad = lam >> 4;

  __shared__ __align__(16) char lds[65536];   // [2][sA 16K | sB 16K]

  f32x4 acc[4][4];
#pragma unroll
  for (int i = 0; i < 4; ++i)
#pragma unroll
    for (int j = 0; j < 4; ++j) acc[i][j] = {};

  const int sm = (w * 32) + (lam >> 3);
  const int sc = (lam & 7);

#define GSTAGE(k0, buf)                                                       \
  {                                                                           \
    char* sA_ = lds + (buf) * 32768;                                          \
    char* sB_ = lds + (buf) * 32768 + 16384;                                  \
    _Pragma("unroll")                                                         \
    for (int i = 0; i < 4; ++i) {                                             \
      const int li = w * 4096 + i * 1024;                                     \
      const int m = sm + i * 8;                                               \
      const int c = sc ^ (m & 7);                                             \
      async16(sA_ + li, Ap + (size_t)(bm * 128 + m) * DIM + (k0) + c * 8);    \
      async16(sB_ + li, Bw + (size_t)(bn * 128 + m) * DIM + (k0) + c * 8);    \
    }                                                                         \
  }

  GSTAGE(0, 0)   // 8 loads/wave in flight

  for (int t = 0; t < DIM / 64; ++t) {
    // (1) all waves done reading buf (t+1)&1 (== compute(t-1)'s buffer)
    asm volatile("s_barrier" ::: "memory");
    if (t + 1 < DIM / 64) {
      GSTAGE((t + 1) * 64, (t + 1) & 1)
      // (2) tile t's 8 loads landed everywhere; t+1's 8 stay outstanding
      asm volatile("s_waitcnt vmcnt(8)\n\ts_barrier" ::: "memory");
    } else {
      asm volatile("s_waitcnt vmcnt(0)\n\ts_barrier" ::: "memory");
    }
    const char* sA = lds + (t & 1) * 32768;
    const char* sB = lds + (t & 1) * 32768 + 16384;
#pragma unroll
    for (int kc = 0; kc < 2; ++kc) {
      const int chunk = kc * 4 + quad;
      short8 af[4], bfr[4];
#pragma unroll
      for (int i = 0; i < 4; ++i) {
        const int m = wr * 64 + i * 16 + lane15;
        af[i] = *(const short8*)(sA + m * 128 + ((chunk ^ (m & 7)) * 16));
      }
#pragma unroll
      for (int j = 0; j < 4; ++j) {
        const int n = wc * 64 + j * 16 + lane15;
        bfr[j] = *(const short8*)(sB + n * 128 + ((chunk ^ (n & 7)) * 16));
      }
#pragma unroll
      for (int i = 0; i < 4; ++i)
#pragma unroll
        for (int j = 0; j < 4; ++j)
          acc[i][j] = __builtin_amdgcn_mfma_f32_16x16x32_bf16(af[i], bfr[j], acc[i][j], 0, 0, 0);
    }
  }
#undef GSTAGE

#pragma unroll
  for (int j = 0; j < 4; ++j) {
    const int n = bn * 128 + wc * 64 + j * 16 + lane15;
    const float bv = bias[n];
#pragma unroll
    for (int i = 0; i < 4; ++i) {
      const int mb = bm * 128 + wr * 64 + i * 16 + quad * 4;
#pragma unroll
      for (int r = 0; r < 4; ++r) {
        const int m = mb + r;
        const float val = acc[i][j][r] + bv;
        if (OUT_F32) {
          if (m < Mout) ((float*)D)[(size_t)m * DIM + n] = val;
        } else {
          ((ushort_t*)D)[(size_t)m * DIM + n] = f2bf(val);
        }
      }
    }
  }
}

// ---------------------------------------------------------------------------
// Fused: RMSNorm + 3D RoPE (head-major out)  AND  V -> 32-key panels.
// V panel columns carry the PV fragment permutation: key k -> position
// p = qq*8 + n0*4 + j  (qq=(k>>2)&3, n0=k>>4, j=k&3), matching the K=32
// A-fragment relabel kappa = quad*8 + n0*4 + r <-> key = n0*16 + quad*4 + r.
// ---------------------------------------------------------------------------
__global__ __launch_bounds__(256) void nr_vp(
    const ushort_t* __restrict__ qpre, const ushort_t* __restrict__ kpre,
    const ushort_t* __restrict__ vbf,
    const float* __restrict__ gq, const float* __restrict__ gk,
    const float* __restrict__ freqs,
    const int* __restrict__ seq_lens, const int* __restrict__ grid_sizes,
    ushort_t* __restrict__ qh, ushort_t* __restrict__ kh,
    ushort_t* __restrict__ vp)
{
  const int bx = blockIdx.x;
  const int tid = threadIdx.x;
  __shared__ float wsum[4];
  __shared__ float srstd;
  __shared__ ushort_t tbuf[32][33];

  if (bx >= 2 * LPAD) {
    const int vb = bx - 2 * LPAD;
    const int head = vb / (NT2 * 4);
    const int rem = vb - head * (NT2 * 4);
    const int t2 = rem >> 2;
    const int d0 = (rem & 3) * 32;
    const int l0 = t2 * 32;
    const int tx = tid & 31, ty = tid >> 5;
#pragma unroll
    for (int rr = 0; rr < 4; ++rr)
      tbuf[ty * 4 + rr][tx] = vbf[(size_t)(l0 + ty * 4 + rr) * DIM + head * HD + d0 + tx];
    __syncthreads();
    const int tx2 = ((tx >> 2) & 3) * 8 + (tx >> 4) * 4 + (tx & 3);  // PV perm
#pragma unroll
    for (int rr = 0; rr < 4; ++rr) {
      const int d = d0 + ty * 4 + rr;
      vp[(((size_t)head * NT2 + t2) * HD + d) * KT2 + tx2] = tbuf[tx][ty * 4 + rr];
    }
    return;
  }

  const int row = bx >> 1;
  const int which = bx & 1;
  const ushort_t* src = which ? kpre : qpre;
  const float* g = which ? gk : gq;
  ushort_t* dst = which ? kh : qh;

  float s = 0.f;
  if (tid < 192) {
    uint4 u = *(const uint4*)(src + (size_t)row * DIM + tid * 8);
    const uint32 uu[4] = {u.x, u.y, u.z, u.w};
#pragma unroll
    for (int i = 0; i < 4; ++i) {
      float a = bf2f((ushort_t)(uu[i] & 0xffff));
      float b = bf2f((ushort_t)(uu[i] >> 16));
      s += a * a + b * b;
    }
  }
#pragma unroll
  for (int off = 32; off; off >>= 1) s += __shfl_down(s, off, 64);
  if ((tid & 63) == 0) wsum[tid >> 6] = s;
  __syncthreads();
  if (tid == 0)
    srstd = rsqrtf((wsum[0] + wsum[1] + wsum[2] + wsum[3]) / (float)DIM + 1e-6f);
  __syncthreads();
  const float rstd = srstd;

  const int seq = seq_lens[0];
  const int h_ = grid_sizes[1], w_ = grid_sizes[2];
  const int hw = h_ * w_;
  const int fidx = row / hw;
  const int rem = row - fidx * hw;
  const int hidx = rem / w_;
  const int widx = rem - hidx * w_;
  const bool live = row < seq;

#pragma unroll
  for (int pp = 0; pp < 3; ++pp) {
    const int p = tid + pp * 256;
    const int c = p & 63, head = p >> 6;
    const int e_in = head * HD + 2 * c;
    uint32 xin = *(const uint32*)(src + (size_t)row * DIM + e_in);
    float x0 = bf2f((ushort_t)(xin & 0xffff));
    float x1 = bf2f((ushort_t)(xin >> 16));
    float2 gg = *(const float2*)(g + e_in);
    float y0 = x0 * rstd * gg.x, y1 = x1 * rstd * gg.y;
    const int pos = (c < 22) ? fidx : ((c < 43) ? hidx : widx);
    float4 R = *(const float4*)(freqs + ((size_t)pos * 64 + c) * 4);
    float o0 = R.x * y0 + R.y * y1;
    float o1 = R.z * y0 + R.w * y1;
    uint32 op = live ? ((uint32)f2bf(o0) | ((uint32)f2bf(o1) << 16)) : 0u;
    *(uint32*)(dst + ((size_t)head * LPAD + row) * HD + 2 * c) = op;
  }
}

// ---------------------------------------------------------------------------
// Flash attention, round 14: swapped QK^T + in-register P (round 12) with a
// 3-buffer depth-2 prefetch pipeline and counted vmcnt:
//   per tile: vmcnt(4)+barrier (tile t loaded 2 iters ago; t+1's 4 loads
//   stay in flight) -> STAGE(t+2) -> QK^T/softmax/PV. No vmcnt(0) drain in
//   the main loop. LDS 48K (3 blocks/CU unchanged).
// ---------------------------------------------------------------------------
__global__ __launch_bounds__(256, 3) void attn8(
    const ushort_t* __restrict__ qh, const ushort_t* __restrict__ kh,
    const ushort_t* __restrict__ vp, const int* __restrict__ seq_lens,
    _Float16* __restrict__ op0, _Float16* __restrict__ op1,
    _Float16* __restrict__ op2, _Float16* __restrict__ op3,
    float* __restrict__ lp)
{
  // XCD swizzle: 912 blocks = 8 XCDs x 114; chunk = 6 heads of one qz.
  const int bid = blockIdx.x;
  const int swz = (bid & 7) * 114 + (bid >> 3);
  const int qx = swz % 19;
  const int rest = swz / 19;
  const int head = rest % 12;
  const int qz = rest / 12;
  const int q0 = qx * 128;
  const int tid = threadIdx.x;
  const int w = tid >> 6, lam = tid & 63;
  const int lane15 = lam & 15, quad = lam >> 4;
  const int seq = seq_lens[0];
  _Float16* op = (qz == 0) ? op0 : ((qz == 1) ? op1 : ((qz == 2) ? op2 : op3));

  __shared__ __align__(16) char kbuf[3][8192];      // [32 key][128 bf16], XOR
  __shared__ __align__(16) char vbuf[3][8192];      // PV-fragment granules

  // resident Q: wave w owns rows q0 + w*32 .. +31 (2 q-tiles)
  const ushort_t* qbase = qh + ((size_t)head * LPAD + q0 + w * 32) * HD;
  short8 qf[2][4];
#pragma unroll
  for (int qt = 0; qt < 2; ++qt)
#pragma unroll
    for (int kc = 0; kc < 4; ++kc)
      qf[qt][kc] = *(const short8*)(qbase + (qt * 16 + lane15) * HD + kc * 32 + quad * 8);

  f32x4 o[2][8];
#pragma unroll
  for (int qt = 0; qt < 2; ++qt)
#pragma unroll
    for (int dt = 0; dt < 8; ++dt) o[qt][dt] = {};
  float lacc[2] = {};

  const float c1 = 0.12751744510848893f;   // (1/sqrt(128)) * log2(e)
  const float c2 = 17.312340490667562f;    // 12 * log2(e)

  const ushort_t* khh = kh + (size_t)head * LPAD * HD;
  const ushort_t* vph = vp + (size_t)head * NT2 * HD * KT2;

  const int krow0 = w * 8 + (lam >> 4);       // + i*4
  const int kslot = lam & 15;

#define STAGE(gt, b)                                                     \
  {                                                                      \
    const ushort_t* kg = khh + (size_t)(gt) * (KT2 * HD);                \
    const ushort_t* vg = vph + (size_t)(gt) * (HD * KT2);                \
    _Pragma("unroll")                                                    \
    for (int i = 0; i < 2; ++i) {                                        \
      const int li = w * 2048 + i * 1024;                                \
      const int kr = krow0 + i * 4;                                      \
      const int kc_ = kslot ^ (kr & 15);                                 \
      async16(kbuf[b] + li, kg + kr * HD + kc_ * 8);                     \
      const int G = w * 128 + i * 64 + lam;                              \
      const int vdt = G >> 6, vdd = (G >> 2) & 15, vqq = G & 3;          \
      async16(vbuf[b] + li, vg + (vdt * 16 + vdd) * KT2 + vqq * 8);      \
    }                                                                    \
  }

  const int tbase = qz * NTQ;
  STAGE(tbase, 0)           // 4 loads/wave
  STAGE(tbase + 1, 1)       // 8 outstanding

  for (int t = 0; t < NTQ; ++t) {
    const int bb = t % 3;
    const int gt = tbase + t;
    if (t + 2 < NTQ) {
      // tile t's 4 loads (issued 2 iters ago) landed; t+1's 4 in flight.
      // barrier also: all waves finished reading buf (t-1)%3 == (t+2)%3.
      asm volatile("s_waitcnt vmcnt(4)\n\ts_barrier" ::: "memory");
      STAGE(gt + 2, (t + 2) % 3)
    } else {
      asm volatile("s_waitcnt vmcnt(0)\n\ts_barrier" ::: "memory");
    }

    // ---- QK^T (swapped: A=K, B=Q -> S^T) ----
    f32x4 S[2][2];
    S[0][0] = {}; S[0][1] = {}; S[1][0] = {}; S[1][1] = {};
#pragma unroll
    for (int n0 = 0; n0 < 2; ++n0)
#pragma unroll
      for (int kc = 0; kc < 4; ++kc) {
        short8 kf = *(const short8*)(kbuf[bb] + (n0 * 16 + lane15) * 256 +
                                     (((kc * 4 + quad) ^ lane15) * 16));
#pragma unroll
        for (int qt = 0; qt < 2; ++qt)
          S[qt][n0] = __builtin_amdgcn_mfma_f32_16x16x32_bf16(kf, qf[qt][kc], S[qt][n0], 0, 0, 0);
      }

    // ---- fixed-max softmax -> in-register K=32 A-fragments ----
    const bool edge = (gt + 1) * KT2 > seq;   // wave-uniform; true once
    short8 pa8[2];
#pragma unroll
    for (int qt = 0; qt < 2; ++qt) {
      float ev[8];
#pragma unroll
      for (int n0 = 0; n0 < 2; ++n0)
#pragma unroll
        for (int r = 0; r < 4; ++r)
          ev[n0 * 4 + r] = exp2f(S[qt][n0][r] * c1 - c2);
      if (edge) {
#pragma unroll
        for (int n0 = 0; n0 < 2; ++n0) {
          const int kb0 = gt * KT2 + n0 * 16 + quad * 4;
#pragma unroll
          for (int r = 0; r < 4; ++r)
            if (kb0 + r >= seq) ev[n0 * 4 + r] = 0.f;
        }
      }
      float s8 = ((ev[0] + ev[1]) + (ev[2] + ev[3])) +
                 ((ev[4] + ev[5]) + (ev[6] + ev[7]));
      lacc[qt] += s8;
      union { uint32 u[4]; short8 s; } pk;
      pk.u[0] = cvtpk(ev[0], ev[1]);
      pk.u[1] = cvtpk(ev[2], ev[3]);
      pk.u[2] = cvtpk(ev[4], ev[5]);
      pk.u[3] = cvtpk(ev[6], ev[7]);
      pa8[qt] = pk.s;
    }

    // ---- PV (K=32 builtin MFMA, P from registers) ----
#pragma unroll
    for (int dt = 0; dt < 8; ++dt) {
      short8 vf = *(const short8*)(vbuf[bb] + dt * 1024 + lane15 * 64 + quad * 16);
#pragma unroll
      for (int qt = 0; qt < 2; ++qt)
        o[qt][dt] = __builtin_amdgcn_mfma_f32_16x16x32_bf16(pa8[qt], vf, o[qt][dt], 0, 0, 0);
    }
  }
#undef STAGE

  // ---- partial l + normalized fp16 partial o ----
#pragma unroll
  for (int qt = 0; qt < 2; ++qt) {
    float l = lacc[qt];
    l += __shfl_xor(l, 16, 64);
    l += __shfl_xor(l, 32, 64);
    // l = sum over all keys for q-row (qt*16 + lane15), uniform over quads
    if (lam < 16)
      lp[((size_t)qz * NH + head) * LPAD + q0 + w * 32 + qt * 16 + lam] = l;
    const float lrcp = 1.0f / l;
    float linv[4];
#pragma unroll
    for (int r = 0; r < 4; ++r) linv[r] = __shfl(lrcp, quad * 4 + r, 64);
#pragma unroll
    for (int dt = 0; dt < 8; ++dt)
#pragma unroll
      for (int r = 0; r < 4; ++r) {
        const int m = q0 + w * 32 + qt * 16 + quad * 4 + r;
        op[(size_t)m * DIM + head * HD + dt * 16 + lane15] =
            (_Float16)(o[qt][dt][r] * linv[r]);
      }
  }
}

// ---------------------------------------------------------------------------
// Merge 4 partials: out = sum(o_h * l_h) / sum(l_h) -> bf16.
// ---------------------------------------------------------------------------
__global__ void merge(const _Float16* __restrict__ o0, const _Float16* __restrict__ o1,
                      const _Float16* __restrict__ o2, const _Float16* __restrict__ o3,
                      const float* __restrict__ lp, ushort_t* __restrict__ attno)
{
  const int i = blockIdx.x * 256 + threadIdx.x;
  const int e = i * 8;
  const int m = e / DIM;
  const int head = (e - m * DIM) >> 7;
  float l[4];
#pragma unroll
  for (int h = 0; h < 4; ++h) l[h] = lp[((size_t)h * NH + head) * LPAD + m];
  const float inv = 1.0f / (l[0] + l[1] + l[2] + l[3]);
  half8 a = *(const half8*)(o0 + e);
  half8 b = *(const half8*)(o1 + e);
  half8 c = *(const half8*)(o2 + e);
  half8 d = *(const half8*)(o3 + e);
  const float w0 = l[0] * inv, w1 = l[1] * inv, w2 = l[2] * inv, w3 = l[3] * inv;
  float f[8];
#pragma unroll
  for (int j = 0; j < 8; ++j)
    f[j] = (float)a[j] * w0 + (float)b[j] * w1 + (float)c[j] * w2 + (float)d[j] * w3;
  *(uint4*)(attno + e) = pack8(f);
}

// ---------------------------------------------------------------------------
extern "C" void kernel_launch(void* const* d_in, const int* in_sizes, int n_in,
                              void* d_out, int out_size, void* d_ws, size_t ws_size,
                              hipStream_t stream)
{
  const float* x  = (const float*)d_in[0];
  const float* Wq = (const float*)d_in[1];
  const float* bq = (const float*)d_in[2];
  const float* Wk = (const float*)d_in[3];
  const float* bk = (const float*)d_in[4];
  const float* Wv = (const float*)d_in[5];
  const float* bv = (const float*)d_in[6];
  const float* Wo = (const float*)d_in[7];
  const float* bo = (const float*)d_in[8];
  const float* gq = (const float*)d_in[9];
  const float* gk = (const float*)d_in[10];
  const int* seq_lens   = (const int*)d_in[11];
  const int* grid_sizes = (const int*)d_in[12];
  const float* freqs    = (const float*)d_in[13];
  float* out = (float*)d_out;

  const size_t BUF = (size_t)LPAD * DIM * 2;       // 7,471,104 B
  const size_t WB  = (size_t)DIM * DIM * 2;        // 4,718,592 B
  char* ws = (char*)d_ws;
  dim3 blk(256);

  ushort_t* xbf  = (ushort_t*)(ws);                     // then vp, then attno
  ushort_t* wqb  = (ushort_t*)(ws + BUF);               // op3 after qkv gemm
  ushort_t* wkb  = (ushort_t*)(ws + BUF + WB);
  ushort_t* wvb  = (ushort_t*)(ws + BUF + 2 * WB);      // lp after qkv gemm
  ushort_t* wob  = (ushort_t*)(ws + BUF + 3 * WB);      // live until out gemm
  ushort_t* qpre = (ushort_t*)(ws + BUF + 4 * WB);      // op0 after nr_vp
  ushort_t* kpre = (ushort_t*)(ws + 2 * BUF + 4 * WB);  // op1 after nr_vp
  ushort_t* qh   = (ushort_t*)(ws + 3 * BUF + 4 * WB);
  ushort_t* kh   = (ushort_t*)(ws + 4 * BUF + 4 * WB);
  ushort_t* vbf  = (ushort_t*)(ws + 5 * BUF + 4 * WB);  // op2 after nr_vp
  ushort_t* vp    = xbf;                // xbf dead after qkv gemm
  ushort_t* attno = xbf;                // vp dead after attn
  _Float16* op0 = (_Float16*)qpre;
  _Float16* op1 = (_Float16*)kpre;
  _Float16* op2 = (_Float16*)vbf;
  _Float16* op3 = (_Float16*)wqb;       // wqb+wkb = 9.4 MB >= BUF
  float*    lp  = (float*)wvb;

  cvt_all<<<dim3(LPAD * DIM / 2048, 5), blk, 0, stream>>>(
      x, Wq, Wk, Wv, Wo, xbf, wqb, wkb, wvb, wob);
  gemm_bt<0><<<dim3(228, 3), blk, 0, stream>>>(
      xbf, wqb, wkb, wvb, bq, bk, bv, qpre, kpre, vbf, 0);
  nr_vp<<<dim3(2 * LPAD + NH * NT2 * 4), blk, 0, stream>>>(
      qpre, kpre, vbf, gq, gk, freqs, seq_lens, grid_sizes, qh, kh, vp);
  attn8<<<dim3(912), blk, 0, stream>>>(
      qh, kh, vp, seq_lens, op0, op1, op2, op3, lp);
  merge<<<dim3(LPAD * DIM / 2048), blk, 0, stream>>>(op0, op1, op2, op3, lp, attno);
  gemm_bt<1><<<dim3(228, 1), blk, 0, stream>>>(
      attno, wob, wob, wob, bo, bo, bo, out, out, out, LSEQ);
}

// Round 9
// 262.142 us; speedup vs baseline: 1.0389x; 1.0389x over previous
//
#include <hip/hip_runtime.h>
#include <hip/hip_bf16.h>
#include <stdint.h>

// WanSelfAttention on gfx950, round 15.
// attn8: KV-split 4->3 (grid 912->684). Unified VGPR+AGPR usage (~144/wave:
// 64 AGPR acc + 80 VGPR) caps residency at 3 blocks/CU = 768 -> the 912
// grid ran as 768 + 144-block tail (measured occ 21% == two-phase model).
// 684 <= 768 -> single co-resident phase; per-block tiles 19->25/26 (+33%)
// but makespan ~ -35%. Pipeline reverted to 2-buf __syncthreads form
// (counted-vmcnt was neutral in r14). merge: 3 partials.
// gemm_bt: exact round-13 structure (r14's barrier/vmcnt split cost +7us).

#define DIM  1536
#define NH   12
#define HD   128
#define LSEQ 2400
#define LPAD 2432
#define KT2  32
#define NT2  (LPAD / KT2)    // 76 global 32-key tiles

typedef __attribute__((ext_vector_type(8))) short short8;
typedef __attribute__((ext_vector_type(8))) _Float16 half8;
typedef __attribute__((ext_vector_type(4))) float f32x4;
typedef unsigned short ushort_t;
typedef unsigned int   uint32;

__device__ __forceinline__ ushort_t f2bf(float f) {
  union { float f; unsigned u; } v; v.f = f;
  unsigned r = (v.u + 0x7fffu + ((v.u >> 16) & 1u)) >> 16;   // RNE
  return (ushort_t)r;
}
__device__ __forceinline__ float bf2f(ushort_t h) {
  union { unsigned u; float f; } v; v.u = ((unsigned)h) << 16;
  return v.f;
}
__device__ __forceinline__ uint32 cvtpk(float lo, float hi) {
  uint32 r;
  asm("v_cvt_pk_bf16_f32 %0, %1, %2" : "=v"(r) : "v"(lo), "v"(hi));
  return r;
}
__device__ __forceinline__ void async16(void* lds, const void* g) {
  __builtin_amdgcn_global_load_lds(
      (const __attribute__((address_space(1))) uint32*)g,
      (__attribute__((address_space(3))) uint32*)lds, 16, 0, 0);
}
__device__ __forceinline__ uint4 pack8(const float* f) {
  uint4 u;
  u.x = (uint32)f2bf(f[0]) | ((uint32)f2bf(f[1]) << 16);
  u.y = (uint32)f2bf(f[2]) | ((uint32)f2bf(f[3]) << 16);
  u.z = (uint32)f2bf(f[4]) | ((uint32)f2bf(f[5]) << 16);
  u.w = (uint32)f2bf(f[6]) | ((uint32)f2bf(f[7]) << 16);
  return u;
}

// ---------------------------------------------------------------------------
// All f32->bf16 conversions in one launch. y=0: x (pad to LPAD, zeros);
// y=1..4: Wq/Wk/Wv/Wo.
// ---------------------------------------------------------------------------
__global__ void cvt_all(const float* __restrict__ x,
                        const float* __restrict__ W0, const float* __restrict__ W1,
                        const float* __restrict__ W2, const float* __restrict__ W3,
                        ushort_t* __restrict__ xd,
                        ushort_t* __restrict__ d0, ushort_t* __restrict__ d1,
                        ushort_t* __restrict__ d2, ushort_t* __restrict__ d3)
{
  const int z = blockIdx.y;
  const int i = blockIdx.x * 256 + threadIdx.x;
  if (z == 0) {
    uint4 u = {0, 0, 0, 0};
    if (i * 8 < LSEQ * DIM) {
      float f[8];
      *(float4*)f = *(const float4*)(x + i * 8);
      *(float4*)(f + 4) = *(const float4*)(x + i * 8 + 4);
      u = pack8(f);
    }
    *(uint4*)(xd + i * 8) = u;
    return;
  }
  if (blockIdx.x >= DIM * DIM / 2048) return;
  const float* s = (z == 1) ? W0 : ((z == 2) ? W1 : ((z == 3) ? W2 : W3));
  ushort_t* d    = (z == 1) ? d0 : ((z == 2) ? d1 : ((z == 3) ? d2 : d3));
  float f[8];
  *(float4*)f = *(const float4*)(s + i * 8);
  *(float4*)(f + 4) = *(const float4*)(s + i * 8 + 4);
  *(uint4*)(d + i * 8) = pack8(f);
}

// ---------------------------------------------------------------------------
// GEMM (round-13 structure): double-buffered async LDS staging,
// STAGE(t+1) -> compute(t) -> __syncthreads. XCD-swizzled blockIdx.
// ---------------------------------------------------------------------------
template<int OUT_F32>
__global__ __launch_bounds__(256) void gemm_bt(
    const ushort_t* __restrict__ Ap,
    const ushort_t* __restrict__ B0, const ushort_t* __restrict__ B1, const ushort_t* __restrict__ B2,
    const float* __restrict__ b0, const float* __restrict__ b1, const float* __restrict__ b2,
    void* __restrict__ D0, void* __restrict__ D1, void* __restrict__ D2,
    int Mout)
{
  const int z = blockIdx.y;
  const ushort_t* Bw  = (z == 0) ? B0 : ((z == 1) ? B1 : B2);
  const float* bias   = (z == 0) ? b0 : ((z == 1) ? b1 : b2);
  void* D             = (z == 0) ? D0 : ((z == 1) ? D1 : D2);

  // bijective XCD swizzle for nwg=228: q=28, r=4
  const int bid = blockIdx.x;
  const int x_ = bid & 7, k_ = bid >> 3;
  const int swz = (x_ < 4 ? x_ * 29 : 116 + (x_ - 4) * 28) + k_;
  const int bm = swz / 12, bn = swz % 12;
  const int tid = threadIdx.x;
  const int w = tid >> 6, lam = tid & 63;
  const int wr = w >> 1, wc = w & 1;
  const int lane15 = lam & 15, quad = lam >> 4;

  __shared__ __align__(16) char lds[65536];   // [2][sA 16K | sB 16K]

  f32x4 acc[4][4];
#pragma unroll
  for (int i = 0; i < 4; ++i)
#pragma unroll
    for (int j = 0; j < 4; ++j) acc[i][j] = {};

  const int sm = (w * 32) + (lam >> 3);
  const int sc = (lam & 7);

#define GSTAGE(k0, buf)                                                       \
  {                                                                           \
    char* sA_ = lds + (buf) * 32768;                                          \
    char* sB_ = lds + (buf) * 32768 + 16384;                                  \
    _Pragma("unroll")                                                         \
    for (int i = 0; i < 4; ++i) {                                             \
      const int li = w * 4096 + i * 1024;                                     \
      const int m = sm + i * 8;                                               \
      const int c = sc ^ (m & 7);                                             \
      async16(sA_ + li, Ap + (size_t)(bm * 128 + m) * DIM + (k0) + c * 8);    \
      async16(sB_ + li, Bw + (size_t)(bn * 128 + m) * DIM + (k0) + c * 8);    \
    }                                                                         \
  }

  GSTAGE(0, 0)
  __syncthreads();

  for (int t = 0; t < DIM / 64; ++t) {
    if (t + 1 < DIM / 64) GSTAGE((t + 1) * 64, (t + 1) & 1)
    const char* sA = lds + (t & 1) * 32768;
    const char* sB = lds + (t & 1) * 32768 + 16384;
#pragma unroll
    for (int kc = 0; kc < 2; ++kc) {
      const int chunk = kc * 4 + quad;
      short8 af[4], bfr[4];
#pragma unroll
      for (int i = 0; i < 4; ++i) {
        const int m = wr * 64 + i * 16 + lane15;
        af[i] = *(const short8*)(sA + m * 128 + ((chunk ^ (m & 7)) * 16));
      }
#pragma unroll
      for (int j = 0; j < 4; ++j) {
        const int n = wc * 64 + j * 16 + lane15;
        bfr[j] = *(const short8*)(sB + n * 128 + ((chunk ^ (n & 7)) * 16));
      }
#pragma unroll
      for (int i = 0; i < 4; ++i)
#pragma unroll
        for (int j = 0; j < 4; ++j)
          acc[i][j] = __builtin_amdgcn_mfma_f32_16x16x32_bf16(af[i], bfr[j], acc[i][j], 0, 0, 0);
    }
    __syncthreads();   // staging(t+1) drained; buf[t&1] free for t+2
  }
#undef GSTAGE

#pragma unroll
  for (int j = 0; j < 4; ++j) {
    const int n = bn * 128 + wc * 64 + j * 16 + lane15;
    const float bv = bias[n];
#pragma unroll
    for (int i = 0; i < 4; ++i) {
      const int mb = bm * 128 + wr * 64 + i * 16 + quad * 4;
#pragma unroll
      for (int r = 0; r < 4; ++r) {
        const int m = mb + r;
        const float val = acc[i][j][r] + bv;
        if (OUT_F32) {
          if (m < Mout) ((float*)D)[(size_t)m * DIM + n] = val;
        } else {
          ((ushort_t*)D)[(size_t)m * DIM + n] = f2bf(val);
        }
      }
    }
  }
}

// ---------------------------------------------------------------------------
// Fused: RMSNorm + 3D RoPE (head-major out)  AND  V -> 32-key panels.
// V panel columns carry the PV fragment permutation: key k -> position
// p = qq*8 + n0*4 + j  (qq=(k>>2)&3, n0=k>>4, j=k&3), matching the K=32
// A-fragment relabel kappa = quad*8 + n0*4 + r <-> key = n0*16 + quad*4 + r.
// ---------------------------------------------------------------------------
__global__ __launch_bounds__(256) void nr_vp(
    const ushort_t* __restrict__ qpre, const ushort_t* __restrict__ kpre,
    const ushort_t* __restrict__ vbf,
    const float* __restrict__ gq, const float* __restrict__ gk,
    const float* __restrict__ freqs,
    const int* __restrict__ seq_lens, const int* __restrict__ grid_sizes,
    ushort_t* __restrict__ qh, ushort_t* __restrict__ kh,
    ushort_t* __restrict__ vp)
{
  const int bx = blockIdx.x;
  const int tid = threadIdx.x;
  __shared__ float wsum[4];
  __shared__ float srstd;
  __shared__ ushort_t tbuf[32][33];

  if (bx >= 2 * LPAD) {
    const int vb = bx - 2 * LPAD;
    const int head = vb / (NT2 * 4);
    const int rem = vb - head * (NT2 * 4);
    const int t2 = rem >> 2;
    const int d0 = (rem & 3) * 32;
    const int l0 = t2 * 32;
    const int tx = tid & 31, ty = tid >> 5;
#pragma unroll
    for (int rr = 0; rr < 4; ++rr)
      tbuf[ty * 4 + rr][tx] = vbf[(size_t)(l0 + ty * 4 + rr) * DIM + head * HD + d0 + tx];
    __syncthreads();
    const int tx2 = ((tx >> 2) & 3) * 8 + (tx >> 4) * 4 + (tx & 3);  // PV perm
#pragma unroll
    for (int rr = 0; rr < 4; ++rr) {
      const int d = d0 + ty * 4 + rr;
      vp[(((size_t)head * NT2 + t2) * HD + d) * KT2 + tx2] = tbuf[tx][ty * 4 + rr];
    }
    return;
  }

  const int row = bx >> 1;
  const int which = bx & 1;
  const ushort_t* src = which ? kpre : qpre;
  const float* g = which ? gk : gq;
  ushort_t* dst = which ? kh : qh;

  float s = 0.f;
  if (tid < 192) {
    uint4 u = *(const uint4*)(src + (size_t)row * DIM + tid * 8);
    const uint32 uu[4] = {u.x, u.y, u.z, u.w};
#pragma unroll
    for (int i = 0; i < 4; ++i) {
      float a = bf2f((ushort_t)(uu[i] & 0xffff));
      float b = bf2f((ushort_t)(uu[i] >> 16));
      s += a * a + b * b;
    }
  }
#pragma unroll
  for (int off = 32; off; off >>= 1) s += __shfl_down(s, off, 64);
  if ((tid & 63) == 0) wsum[tid >> 6] = s;
  __syncthreads();
  if (tid == 0)
    srstd = rsqrtf((wsum[0] + wsum[1] + wsum[2] + wsum[3]) / (float)DIM + 1e-6f);
  __syncthreads();
  const float rstd = srstd;

  const int seq = seq_lens[0];
  const int h_ = grid_sizes[1], w_ = grid_sizes[2];
  const int hw = h_ * w_;
  const int fidx = row / hw;
  const int rem = row - fidx * hw;
  const int hidx = rem / w_;
  const int widx = rem - hidx * w_;
  const bool live = row < seq;

#pragma unroll
  for (int pp = 0; pp < 3; ++pp) {
    const int p = tid + pp * 256;
    const int c = p & 63, head = p >> 6;
    const int e_in = head * HD + 2 * c;
    uint32 xin = *(const uint32*)(src + (size_t)row * DIM + e_in);
    float x0 = bf2f((ushort_t)(xin & 0xffff));
    float x1 = bf2f((ushort_t)(xin >> 16));
    float2 gg = *(const float2*)(g + e_in);
    float y0 = x0 * rstd * gg.x, y1 = x1 * rstd * gg.y;
    const int pos = (c < 22) ? fidx : ((c < 43) ? hidx : widx);
    float4 R = *(const float4*)(freqs + ((size_t)pos * 64 + c) * 4);
    float o0 = R.x * y0 + R.y * y1;
    float o1 = R.z * y0 + R.w * y1;
    uint32 op = live ? ((uint32)f2bf(o0) | ((uint32)f2bf(o1) << 16)) : 0u;
    *(uint32*)(dst + ((size_t)head * LPAD + row) * HD + 2 * c) = op;
  }
}

// ---------------------------------------------------------------------------
// Flash attention, round 15: swapped QK^T + in-register P (round 12 core),
// 3-way KV split. Grid 684 = 12 heads x 19 q-blocks x 3 quarters <= 768
// resident capacity (3 blocks/CU, unified-reg limited) -> single phase.
// qz tiles: 0-24 / 25-49 / 50-75 (runtime ntq 25/25/26). 2-buf pipeline.
// ---------------------------------------------------------------------------
__global__ __launch_bounds__(256, 3) void attn8(
    const ushort_t* __restrict__ qh, const ushort_t* __restrict__ kh,
    const ushort_t* __restrict__ vp, const int* __restrict__ seq_lens,
    _Float16* __restrict__ op0, _Float16* __restrict__ op1,
    _Float16* __restrict__ op2, float* __restrict__ lp)
{
  // bijective XCD swizzle for nwg=684 = 8*85 + 4 (m204)
  const int bid = blockIdx.x;
  const int x_ = bid & 7, k_ = bid >> 3;
  const int swz = (x_ < 4 ? x_ * 86 : 344 + (x_ - 4) * 85) + k_;
  const int qz = swz / 228;
  const int rem_ = swz - qz * 228;
  const int head = rem_ / 19;
  const int qx = rem_ - head * 19;
  const int q0 = qx * 128;
  const int tbase = qz * 25;
  const int ntq = 25 + (qz == 2);
  const int tid = threadIdx.x;
  const int w = tid >> 6, lam = tid & 63;
  const int lane15 = lam & 15, quad = lam >> 4;
  const int seq = seq_lens[0];
  _Float16* op = (qz == 0) ? op0 : ((qz == 1) ? op1 : op2);

  __shared__ __align__(16) char kbuf[2][8192];      // [32 key][128 bf16], XOR
  __shared__ __align__(16) char vbuf[2][8192];      // PV-fragment granules

  // resident Q: wave w owns rows q0 + w*32 .. +31 (2 q-tiles)
  const ushort_t* qbase = qh + ((size_t)head * LPAD + q0 + w * 32) * HD;
  short8 qf[2][4];
#pragma unroll
  for (int qt = 0; qt < 2; ++qt)
#pragma unroll
    for (int kc = 0; kc < 4; ++kc)
      qf[qt][kc] = *(const short8*)(qbase + (qt * 16 + lane15) * HD + kc * 32 + quad * 8);

  f32x4 o[2][8];
#pragma unroll
  for (int qt = 0; qt < 2; ++qt)
#pragma unroll
    for (int dt = 0; dt < 8; ++dt) o[qt][dt] = {};
  float lacc[2] = {};

  const float c1 = 0.12751744510848893f;   // (1/sqrt(128)) * log2(e)
  const float c2 = 17.312340490667562f;    // 12 * log2(e)

  const ushort_t* khh = kh + (size_t)head * LPAD * HD;
  const ushort_t* vph = vp + (size_t)head * NT2 * HD * KT2;

  const int krow0 = w * 8 + (lam >> 4);       // + i*4
  const int kslot = lam & 15;

#define STAGE(gt, b)                                                     \
  {                                                                      \
    const ushort_t* kg = khh + (size_t)(gt) * (KT2 * HD);                \
    const ushort_t* vg = vph + (size_t)(gt) * (HD * KT2);                \
    _Pragma("unroll")                                                    \
    for (int i = 0; i < 2; ++i) {                                        \
      const int li = w * 2048 + i * 1024;                                \
      const int kr = krow0 + i * 4;                                      \
      const int kc_ = kslot ^ (kr & 15);                                 \
      async16(kbuf[b] + li, kg + kr * HD + kc_ * 8);                     \
      const int G = w * 128 + i * 64 + lam;                              \
      const int vdt = G >> 6, vdd = (G >> 2) & 15, vqq = G & 3;          \
      async16(vbuf[b] + li, vg + (vdt * 16 + vdd) * KT2 + vqq * 8);      \
    }                                                                    \
  }

  STAGE(tbase, 0)
  __syncthreads();

  for (int t = 0; t < ntq; ++t) {
    const int b = t & 1;
    const int gt = tbase + t;
    if (t + 1 < ntq) STAGE(gt + 1, b ^ 1)

    // ---- QK^T (swapped: A=K, B=Q -> S^T) ----
    f32x4 S[2][2];
    S[0][0] = {}; S[0][1] = {}; S[1][0] = {}; S[1][1] = {};
#pragma unroll
    for (int n0 = 0; n0 < 2; ++n0)
#pragma unroll
      for (int kc = 0; kc < 4; ++kc) {
        short8 kf = *(const short8*)(kbuf[b] + (n0 * 16 + lane15) * 256 +
                                     (((kc * 4 + quad) ^ lane15) * 16));
#pragma unroll
        for (int qt = 0; qt < 2; ++qt)
          S[qt][n0] = __builtin_amdgcn_mfma_f32_16x16x32_bf16(kf, qf[qt][kc], S[qt][n0], 0, 0, 0);
      }

    // ---- fixed-max softmax -> in-register K=32 A-fragments ----
    const bool edge = (gt + 1) * KT2 > seq;   // wave-uniform; true once
    short8 pa8[2];
#pragma unroll
    for (int qt = 0; qt < 2; ++qt) {
      float ev[8];
#pragma unroll
      for (int n0 = 0; n0 < 2; ++n0)
#pragma unroll
        for (int r = 0; r < 4; ++r)
          ev[n0 * 4 + r] = exp2f(S[qt][n0][r] * c1 - c2);
      if (edge) {
#pragma unroll
        for (int n0 = 0; n0 < 2; ++n0) {
          const int kb0 = gt * KT2 + n0 * 16 + quad * 4;
#pragma unroll
          for (int r = 0; r < 4; ++r)
            if (kb0 + r >= seq) ev[n0 * 4 + r] = 0.f;
        }
      }
      float s8 = ((ev[0] + ev[1]) + (ev[2] + ev[3])) +
                 ((ev[4] + ev[5]) + (ev[6] + ev[7]));
      lacc[qt] += s8;
      union { uint32 u[4]; short8 s; } pk;
      pk.u[0] = cvtpk(ev[0], ev[1]);
      pk.u[1] = cvtpk(ev[2], ev[3]);
      pk.u[2] = cvtpk(ev[4], ev[5]);
      pk.u[3] = cvtpk(ev[6], ev[7]);
      pa8[qt] = pk.s;
    }

    // ---- PV (K=32 builtin MFMA, P from registers) ----
#pragma unroll
    for (int dt = 0; dt < 8; ++dt) {
      short8 vf = *(const short8*)(vbuf[b] + dt * 1024 + lane15 * 64 + quad * 16);
#pragma unroll
      for (int qt = 0; qt < 2; ++qt)
        o[qt][dt] = __builtin_amdgcn_mfma_f32_16x16x32_bf16(pa8[qt], vf, o[qt][dt], 0, 0, 0);
    }
    __syncthreads();
  }
#undef STAGE

  // ---- partial l + normalized fp16 partial o ----
#pragma unroll
  for (int qt = 0; qt < 2; ++qt) {
    float l = lacc[qt];
    l += __shfl_xor(l, 16, 64);
    l += __shfl_xor(l, 32, 64);
    // l = sum over all keys for q-row (qt*16 + lane15), uniform over quads
    if (lam < 16)
      lp[((size_t)qz * NH + head) * LPAD + q0 + w * 32 + qt * 16 + lam] = l;
    const float lrcp = 1.0f / l;
    float linv[4];
#pragma unroll
    for (int r = 0; r < 4; ++r) linv[r] = __shfl(lrcp, quad * 4 + r, 64);
#pragma unroll
    for (int dt = 0; dt < 8; ++dt)
#pragma unroll
      for (int r = 0; r < 4; ++r) {
        const int m = q0 + w * 32 + qt * 16 + quad * 4 + r;
        op[(size_t)m * DIM + head * HD + dt * 16 + lane15] =
            (_Float16)(o[qt][dt][r] * linv[r]);
      }
  }
}

// ---------------------------------------------------------------------------
// Merge 3 partials: out = sum(o_h * l_h) / sum(l_h) -> bf16.
// ---------------------------------------------------------------------------
__global__ void merge(const _Float16* __restrict__ o0, const _Float16* __restrict__ o1,
                      const _Float16* __restrict__ o2,
                      const float* __restrict__ lp, ushort_t* __restrict__ attno)
{
  const int i = blockIdx.x * 256 + threadIdx.x;
  const int e = i * 8;
  const int m = e / DIM;
  const int head = (e - m * DIM) >> 7;
  float l[3];
#pragma unroll
  for (int h = 0; h < 3; ++h) l[h] = lp[((size_t)h * NH + head) * LPAD + m];
  const float inv = 1.0f / (l[0] + l[1] + l[2]);
  half8 a = *(const half8*)(o0 + e);
  half8 b = *(const half8*)(o1 + e);
  half8 c = *(const half8*)(o2 + e);
  const float w0 = l[0] * inv, w1 = l[1] * inv, w2 = l[2] * inv;
  float f[8];
#pragma unroll
  for (int j = 0; j < 8; ++j)
    f[j] = (float)a[j] * w0 + (float)b[j] * w1 + (float)c[j] * w2;
  *(uint4*)(attno + e) = pack8(f);
}

// ---------------------------------------------------------------------------
extern "C" void kernel_launch(void* const* d_in, const int* in_sizes, int n_in,
                              void* d_out, int out_size, void* d_ws, size_t ws_size,
                              hipStream_t stream)
{
  const float* x  = (const float*)d_in[0];
  const float* Wq = (const float*)d_in[1];
  const float* bq = (const float*)d_in[2];
  const float* Wk = (const float*)d_in[3];
  const float* bk = (const float*)d_in[4];
  const float* Wv = (const float*)d_in[5];
  const float* bv = (const float*)d_in[6];
  const float* Wo = (const float*)d_in[7];
  const float* bo = (const float*)d_in[8];
  const float* gq = (const float*)d_in[9];
  const float* gk = (const float*)d_in[10];
  const int* seq_lens   = (const int*)d_in[11];
  const int* grid_sizes = (const int*)d_in[12];
  const float* freqs    = (const float*)d_in[13];
  float* out = (float*)d_out;

  const size_t BUF = (size_t)LPAD * DIM * 2;       // 7,471,104 B
  const size_t WB  = (size_t)DIM * DIM * 2;        // 4,718,592 B
  char* ws = (char*)d_ws;
  dim3 blk(256);

  ushort_t* xbf  = (ushort_t*)(ws);                     // then vp, then attno
  ushort_t* wqb  = (ushort_t*)(ws + BUF);
  ushort_t* wkb  = (ushort_t*)(ws + BUF + WB);
  ushort_t* wvb  = (ushort_t*)(ws + BUF + 2 * WB);      // lp after qkv gemm
  ushort_t* wob  = (ushort_t*)(ws + BUF + 3 * WB);      // live until out gemm
  ushort_t* qpre = (ushort_t*)(ws + BUF + 4 * WB);      // op0 after nr_vp
  ushort_t* kpre = (ushort_t*)(ws + 2 * BUF + 4 * WB);  // op1 after nr_vp
  ushort_t* qh   = (ushort_t*)(ws + 3 * BUF + 4 * WB);
  ushort_t* kh   = (ushort_t*)(ws + 4 * BUF + 4 * WB);
  ushort_t* vbf  = (ushort_t*)(ws + 5 * BUF + 4 * WB);  // op2 after nr_vp
  ushort_t* vp    = xbf;                // xbf dead after qkv gemm
  ushort_t* attno = xbf;                // vp dead after attn
  _Float16* op0 = (_Float16*)qpre;
  _Float16* op1 = (_Float16*)kpre;
  _Float16* op2 = (_Float16*)vbf;
  float*    lp  = (float*)wvb;

  cvt_all<<<dim3(LPAD * DIM / 2048, 5), blk, 0, stream>>>(
      x, Wq, Wk, Wv, Wo, xbf, wqb, wkb, wvb, wob);
  gemm_bt<0><<<dim3(228, 3), blk, 0, stream>>>(
      xbf, wqb, wkb, wvb, bq, bk, bv, qpre, kpre, vbf, 0);
  nr_vp<<<dim3(2 * LPAD + NH * NT2 * 4), blk, 0, stream>>>(
      qpre, kpre, vbf, gq, gk, freqs, seq_lens, grid_sizes, qh, kh, vp);
  attn8<<<dim3(684), blk, 0, stream>>>(
      qh, kh, vp, seq_lens, op0, op1, op2, lp);
  merge<<<dim3(LPAD * DIM / 2048), blk, 0, stream>>>(op0, op1, op2, lp, attno);
  gemm_bt<1><<<dim3(228, 1), blk, 0, stream>>>(
      attno, wob, wob, wob, bo, bo, bo, out, out, out, LSEQ);
}